// Round 1
// baseline (302.489 us; speedup 1.0000x reference)
//
#include <hip/hip_runtime.h>
#include <hip/hip_bf16.h>

typedef __attribute__((ext_vector_type(8))) short short8;
typedef __attribute__((ext_vector_type(4))) float floatx4;

#define B_ 8
#define C_IN 256
#define C_OUT 256
#define H_ 128
#define W_ 128
#define S_ 512
#define HW_ (H_*W_)
#define LIN_SCALE 0.04419417382415922f   /* 1/sqrt(512) */
#define CONV_SCALE 0.02083333333333333f  /* 1/sqrt(256*9) */
#define EPS_ 1e-8f

#define TH 8
#define TW 16
#define PH 10
#define PW 18
#define NPIX (PH*PW)      /* 180 halo pixels */
#define NKB 72            /* 8 ci-chunks * 9 taps */
#define NITEM (8*PH*PW)   /* 1440 staging items per ci-chunk */

__device__ __forceinline__ unsigned short f2bf(float f) {
  unsigned u = __builtin_bit_cast(unsigned, f);
  u = (u + 0x7fffu + ((u >> 16) & 1u)) >> 16;
  return (unsigned short)u;
}

// ---------------- kernel 1: style modulation s[b][ci] ----------------
__global__ void k_style(const float* __restrict__ style, const float* __restrict__ mw,
                        const float* __restrict__ mb, float* __restrict__ s) {
  __shared__ float sty[S_];
  const int b = blockIdx.x;
  for (int i = threadIdx.x; i < S_; i += 256) sty[i] = style[b*S_ + i];
  __syncthreads();
  const int ci = threadIdx.x;  // 256 threads
  const float* wr = mw + (size_t)ci*S_;
  float acc = 0.f;
  for (int i = 0; i < S_; ++i) acc += sty[i] * wr[i];
  s[b*C_IN + ci] = acc * LIN_SCALE + mb[ci];
}

// ---------------- kernel 2: demod[b][co] ----------------
__global__ void k_demod(const float* __restrict__ weight, const float* __restrict__ s,
                        float* __restrict__ demod) {
  const int b = blockIdx.x >> 8, co = blockIdx.x & 255;
  const int l = threadIdx.x;  // 64 threads
  const float* wrow = weight + (size_t)co*C_IN*9;
  const float* sb = s + b*C_IN;
  float acc = 0.f;
  for (int idx = l; idx < C_IN*9; idx += 64) {
    float wv = wrow[idx] * sb[idx/9];
    acc += wv*wv;
  }
#pragma unroll
  for (int off = 32; off; off >>= 1) acc += __shfl_down(acc, off, 64);
  if (l == 0) demod[blockIdx.x] = rsqrtf(acc * (CONV_SCALE*CONV_SCALE) + EPS_);
}

// ---------------- kernel 3: pack modulated weights into MFMA A-fragment order ----------------
// layout: frag[((b*72 + kb)*16 + mt)*64 + lane][8] bf16, kb = ci_chunk*9 + tap
// A-frag lane l: co = mt*16 + (l&15), k_in = (l>>4)*8 + j, ci = chunk*32 + k_in
__global__ void k_pack(const float* __restrict__ weight, const float* __restrict__ s,
                       const float* __restrict__ demod, unsigned short* __restrict__ frag) {
  const int bid = blockIdx.x;            // (b*72 + kb)*16 + mt
  const int mt = bid & 15;
  const int kb = (bid >> 4) % NKB;
  const int b  = bid / (NKB*16);
  const int l = threadIdx.x;             // 64 threads
  const int co = mt*16 + (l & 15);
  const int chunk = kb / 9, r = kb % 9;
  const float dm = demod[b*C_OUT + co] * CONV_SCALE;
  const float* sb = s + b*C_IN;
  unsigned v[4];
#pragma unroll
  for (int jj = 0; jj < 4; ++jj) {
    int ci0 = chunk*32 + (l >> 4)*8 + jj*2;
    unsigned lo = f2bf(weight[((size_t)co*C_IN + ci0    )*9 + r] * sb[ci0    ] * dm);
    unsigned hi = f2bf(weight[((size_t)co*C_IN + ci0 + 1)*9 + r] * sb[ci0 + 1] * dm);
    v[jj] = lo | (hi << 16);
  }
  unsigned* dst = (unsigned*)(frag + (size_t)bid*512 + l*8);
  dst[0] = v[0]; dst[1] = v[1]; dst[2] = v[2]; dst[3] = v[3];
}

// ---------------- kernel 4: implicit-GEMM conv ----------------
// block: 128 co x (8x16) pixels, 4 waves as 2(M)x2(N), each wave 4x4 frags of 16x16
__launch_bounds__(256, 2)
__global__ void k_conv(const float* __restrict__ x, const unsigned short* __restrict__ frag,
                       float* __restrict__ out) {
  __shared__ __align__(16) unsigned char lds[2][NPIX*64];
  const int bid = blockIdx.x;
  const int sx = bid & 7, sy = (bid >> 3) & 15, ct = (bid >> 7) & 1, b = bid >> 8;
  const int h0 = sy*TH, w0 = sx*TW;
  const int tid = threadIdx.x;
  const int lane = tid & 63, wv = tid >> 6;
  const int wm = wv >> 1, wn = wv & 1;

  const float* xb = x + (size_t)b*C_IN*HW_;
  const unsigned short* fb = frag + (size_t)b*NKB*16*512 + (size_t)lane*8;

  floatx4 acc[4][4];
#pragma unroll
  for (int m = 0; m < 4; ++m)
#pragma unroll
    for (int n = 0; n < 4; ++n) acc[m][n] = floatx4{0.f, 0.f, 0.f, 0.f};

  float pf[6][4];

  auto issue = [&](int c) {
#pragma unroll
    for (int i = 0; i < 6; ++i) {
      int item = tid + i*256;
      if (item < NITEM) {
        int pw = item % PW;
        int t  = item / PW;
        int ph = t % PH;
        int q  = t / PH;                  // ci-quad 0..7
        int gh = h0 - 1 + ph, gw = w0 - 1 + pw;
        bool inb = ((unsigned)gh < (unsigned)H_) && ((unsigned)gw < (unsigned)W_);
        const float* p = xb + (size_t)(c*32 + q*4)*HW_ + gh*W_ + gw;
#pragma unroll
        for (int u = 0; u < 4; ++u)
          pf[i][u] = inb ? p[u*HW_] : 0.f;
      }
    }
  };
  auto commit = [&](int c) {
    int buf = c & 1;
#pragma unroll
    for (int i = 0; i < 6; ++i) {
      int item = tid + i*256;
      if (item < NITEM) {
        int pw = item % PW;
        int t  = item / PW;
        int ph = t % PH;
        int q  = t / PH;
        int pix = ph*PW + pw;
        unsigned v0 = (unsigned)f2bf(pf[i][0]) | ((unsigned)f2bf(pf[i][1]) << 16);
        unsigned v1 = (unsigned)f2bf(pf[i][2]) | ((unsigned)f2bf(pf[i][3]) << 16);
        int slot = q >> 1, half = q & 1;
        int addr = pix*64 + ((slot ^ ((pix >> 1) & 3)) << 4) + half*8;
        unsigned* d = (unsigned*)(&lds[buf][addr]);
        d[0] = v0; d[1] = v1;
      }
    }
  };

  issue(0);
  commit(0);
  __syncthreads();

  for (int c = 0; c < 8; ++c) {
    if (c < 7) issue(c + 1);
    const unsigned char* cl = lds[c & 1];
#pragma unroll
    for (int r = 0; r < 9; ++r) {
      const int kb = c*9 + r;
      const int dh = r / 3, dw = r % 3;
      short8 a[4];
#pragma unroll
      for (int m = 0; m < 4; ++m) {
        int mt = ct*8 + wm*4 + m;
        a[m] = *(const short8*)(fb + (size_t)(kb*16 + mt)*512);
      }
      short8 bb[4];
#pragma unroll
      for (int n = 0; n < 4; ++n) {
        int nt = wn*4 + n;
        int pix = (nt + dh)*PW + ((lane & 15) + dw);
        int sl = lane >> 4;
        int addr = pix*64 + ((sl ^ ((pix >> 1) & 3)) << 4);
        bb[n] = *(const short8*)(cl + addr);
      }
#pragma unroll
      for (int m = 0; m < 4; ++m)
#pragma unroll
        for (int n = 0; n < 4; ++n)
          acc[m][n] = __builtin_amdgcn_mfma_f32_16x16x32_bf16(a[m], bb[n], acc[m][n], 0, 0, 0);
    }
    if (c < 7) commit(c + 1);
    __syncthreads();
  }

  // epilogue: C/D layout col=lane&15 (pixel), row=(lane>>4)*4+i (co)
  float* ob = out + ((size_t)b*C_OUT + ct*128)*HW_;
  const int tw = lane & 15, rg = lane >> 4;
#pragma unroll
  for (int m = 0; m < 4; ++m) {
#pragma unroll
    for (int n = 0; n < 4; ++n) {
      int co = (wm*4 + m)*16 + rg*4;
      int h = h0 + wn*4 + n;
      float* p = ob + (size_t)co*HW_ + (size_t)h*W_ + w0 + tw;
#pragma unroll
      for (int i = 0; i < 4; ++i) p[i*HW_] = acc[m][n][i];
    }
  }
}

extern "C" void kernel_launch(void* const* d_in, const int* in_sizes, int n_in,
                              void* d_out, int out_size, void* d_ws, size_t ws_size,
                              hipStream_t stream) {
  const float* x      = (const float*)d_in[0];
  const float* style  = (const float*)d_in[1];
  const float* weight = (const float*)d_in[2];
  const float* mod_w  = (const float*)d_in[3];
  const float* mod_b  = (const float*)d_in[4];
  float* out = (float*)d_out;
  char* ws = (char*)d_ws;

  float* s     = (float*)ws;                       // 2048 f32
  float* demod = (float*)(ws + 8192);              // 2048 f32
  unsigned short* frag = (unsigned short*)(ws + 16384); // 9.4 MB bf16 fragments

  k_style<<<B_, 256, 0, stream>>>(style, mod_w, mod_b, s);
  k_demod<<<B_*C_OUT, 64, 0, stream>>>(weight, s, demod);
  k_pack<<<B_*NKB*16, 64, 0, stream>>>(weight, s, demod, frag);
  k_conv<<<B_*2*16*8, 256, 0, stream>>>(x, frag, out);
}